// Round 6
// baseline (1808.962 us; speedup 1.0000x reference)
//
#include <hip/hip_runtime.h>

// ---------------------------------------------------------------------------
// ConstraintLoss — two-phase binned segment-sum (device-atomic op rate on
// MI355X is ~20 G/s memory-side regardless of scope; we replace 20M atomics
// with ~0.6M flush-cursor atomics + LDS accumulation).
//   phase 0: values = sigmoid(pred)  (bf16 table, 4 MB, L2-resident)
//   phase 1: bin nnz entries (p, local_c) into 123 bucket regions via LDS
//            stages (coalesced flushes, 1 atomic per ~32 entries)
//   phase 2: per-bucket LDS accumulate + fused violation + mean reduce
// Overflows (stage or region cap) fall back to device atomics into ax_dev —
// rare, always correct. If ws_size can't hold regions -> round-3 fallback.
// ---------------------------------------------------------------------------

#define WSHIFT  13
#define W       (1 << WSHIFT)   // 8192 constraints per bucket
#define NB_MAX  128
#define STC     64              // LDS stage capacity per bucket
#define FLUSH_T 32              // flush stage when it reaches this many

typedef int   i4 __attribute__((ext_vector_type(4)));
typedef float f4 __attribute__((ext_vector_type(4)));

__device__ __forceinline__ float bf16_to_f32(unsigned short u) {
    union { unsigned int i; float f; } cvt;
    cvt.i = ((unsigned int)u) << 16;
    return cvt.f;
}

__device__ __forceinline__ unsigned short f32_to_bf16_rne(float f) {
    union { float f; unsigned int i; } cvt;
    cvt.f = f;
    unsigned int u = cvt.i;
    u += 0x7FFFu + ((u >> 16) & 1u);
    return (unsigned short)(u >> 16);
}

__global__ void sigmoid_kernel(const float* __restrict__ pred,
                               unsigned short* __restrict__ values, int n) {
    int i = blockIdx.x * blockDim.x + threadIdx.x;
    int stride = gridDim.x * blockDim.x;
    int n4 = n >> 2;
    const f4* p4 = (const f4*)pred;
    for (int j = i; j < n4; j += stride) {
        f4 p = p4[j];
        ushort4 o;
        o.x = f32_to_bf16_rne(1.0f / (1.0f + __expf(-p.x)));
        o.y = f32_to_bf16_rne(1.0f / (1.0f + __expf(-p.y)));
        o.z = f32_to_bf16_rne(1.0f / (1.0f + __expf(-p.z)));
        o.w = f32_to_bf16_rne(1.0f / (1.0f + __expf(-p.w)));
        ((ushort4*)values)[j] = o;
    }
    for (int j = (n4 << 2) + i; j < n; j += stride)
        values[j] = f32_to_bf16_rne(1.0f / (1.0f + __expf(-pred[j])));
}

// flush all buckets whose stage count >= threshold (wave-cooperative)
__device__ __forceinline__ void flush_stages(
        int threshold, int nb, int cap,
        int* cnt, float* sp, unsigned short* sc,
        int* __restrict__ cursor, float* __restrict__ gp,
        unsigned short* __restrict__ gc, float* __restrict__ ax_dev) {
    int wave = threadIdx.x >> 6;
    int lane = threadIdx.x & 63;
    for (int b = wave; b < nb; b += 4) {       // 256 threads = 4 waves
        int cn = cnt[b];
        if (cn > STC) cn = STC;                // >STC entries already fell back
        if (cn >= threshold && cn > 0) {       // wave-uniform condition
            int rbase = 0;
            if (lane == 0) rbase = atomicAdd(&cursor[b], cn);
            rbase = __shfl(rbase, 0, 64);
            for (int i = lane; i < cn; i += 64) {
                float p = sp[b * STC + i];
                unsigned short c = sc[b * STC + i];
                int pos = rbase + i;
                if (pos < cap) {
                    size_t g = (size_t)b * (size_t)cap + (size_t)pos;
                    gp[g] = p;
                    gc[g] = c;
                } else {
                    atomicAdd(&ax_dev[(b << WSHIFT) + (int)c], p);  // rare
                }
            }
            if (lane == 0) cnt[b] = 0;
        }
    }
}

__global__ __launch_bounds__(256) void bin_kernel(
        const int* __restrict__ cidx, const int* __restrict__ vidx,
        const float* __restrict__ coeff, const unsigned short* __restrict__ values,
        float* __restrict__ gp, unsigned short* __restrict__ gc,
        int* __restrict__ cursor, float* __restrict__ ax_dev,
        int nnz, int nb, int cap) {
    __shared__ float          sp[NB_MAX * STC];   // 32 KB
    __shared__ unsigned short sc[NB_MAX * STC];   // 16 KB
    __shared__ int            cnt[NB_MAX];        // 0.5 KB

    for (int b = threadIdx.x; b < nb; b += blockDim.x) cnt[b] = 0;
    __syncthreads();

    const int CHUNK = 2048;                        // 8 entries/thread/round
    int nchunks = (nnz + CHUNK - 1) / CHUNK;
    for (int ch = blockIdx.x; ch < nchunks; ch += gridDim.x) {
        int base = ch * CHUNK;
        #pragma unroll
        for (int k = 0; k < 8; ++k) {
            int j = base + (k << 8) + threadIdx.x;
            if (j < nnz) {
                int ci   = __builtin_nontemporal_load(&cidx[j]);
                int vi   = __builtin_nontemporal_load(&vidx[j]);
                float w  = __builtin_nontemporal_load(&coeff[j]);
                float p  = w * bf16_to_f32(values[vi]);
                int b    = ci >> WSHIFT;
                int slot = atomicAdd(&cnt[b], 1);  // LDS atomic
                if (slot < STC) {
                    sp[b * STC + slot] = p;
                    sc[b * STC + slot] = (unsigned short)(ci & (W - 1));
                } else {
                    atomicAdd(&ax_dev[ci], p);     // stage overflow (rare)
                }
            }
        }
        __syncthreads();
        flush_stages(FLUSH_T, nb, cap, cnt, sp, sc, cursor, gp, gc, ax_dev);
        __syncthreads();
    }
    flush_stages(1, nb, cap, cnt, sp, sc, cursor, gp, gc, ax_dev);  // drain
}

__global__ __launch_bounds__(256) void accum_kernel(
        const float* __restrict__ gp, const unsigned short* __restrict__ gc,
        const int* __restrict__ cursor, const float* __restrict__ ax_dev,
        const float* __restrict__ rhs, const int* __restrict__ sense,
        float* __restrict__ out, int n_constrs, int cap, float inv_n) {
    __shared__ float acc[W];                       // 32 KB
    int b = blockIdx.x;
    for (int i = threadIdx.x; i < W; i += blockDim.x) acc[i] = 0.0f;
    __syncthreads();

    int cn = cursor[b];
    if (cn > cap) cn = cap;                        // overflow went via ax_dev
    const float* bp = gp + (size_t)b * (size_t)cap;
    const unsigned short* bc = gc + (size_t)b * (size_t)cap;
    for (int i = threadIdx.x; i < cn; i += blockDim.x) {
        float p = __builtin_nontemporal_load(&bp[i]);
        unsigned short c = __builtin_nontemporal_load(&bc[i]);
        atomicAdd(&acc[c], p);                     // LDS atomic
    }
    __syncthreads();

    float sum = 0.0f;
    int c0 = b << WSHIFT;
    for (int i = threadIdx.x; i < W; i += blockDim.x) {
        int ci = c0 + i;
        if (ci < n_constrs) {
            float a = acc[i] + ax_dev[ci];
            float d = a - rhs[ci];
            int s = sense[ci];
            sum += (s == 1) ? fmaxf(d, 0.0f)
                 : (s == 2) ? fmaxf(-d, 0.0f)
                 : (s == 3) ? fabsf(d) : 0.0f;
        }
    }
    for (int off = 32; off > 0; off >>= 1)
        sum += __shfl_down(sum, off, 64);
    __shared__ float red[4];
    int lane = threadIdx.x & 63, wave = threadIdx.x >> 6;
    if (lane == 0) red[wave] = sum;
    __syncthreads();
    if (threadIdx.x == 0)
        atomicAdd(out, (red[0] + red[1] + red[2] + red[3]) * inv_n);
}

// ---------------- fallback path (workspace too small) ----------------------
__global__ void scatter_fallback_kernel(const int* __restrict__ cidx,
                                        const int* __restrict__ vidx,
                                        const float* __restrict__ coeff,
                                        const unsigned short* __restrict__ values,
                                        float* __restrict__ ax, int nnz) {
    int i = blockIdx.x * blockDim.x + threadIdx.x;
    int stride = gridDim.x * blockDim.x;
    for (int j = i; j < nnz; j += stride)
        atomicAdd(&ax[cidx[j]], coeff[j] * bf16_to_f32(values[vidx[j]]));
}

__global__ void viol_reduce_kernel(const float* __restrict__ ax,
                                   const float* __restrict__ rhs,
                                   const int* __restrict__ sense,
                                   float* __restrict__ out, int n, float inv_n) {
    int i = blockIdx.x * blockDim.x + threadIdx.x;
    int stride = gridDim.x * blockDim.x;
    float sum = 0.0f;
    for (int j = i; j < n; j += stride) {
        float d = ax[j] - rhs[j];
        int s = sense[j];
        sum += (s == 1) ? fmaxf(d, 0.0f)
             : (s == 2) ? fmaxf(-d, 0.0f)
             : (s == 3) ? fabsf(d) : 0.0f;
    }
    for (int off = 32; off > 0; off >>= 1)
        sum += __shfl_down(sum, off, 64);
    __shared__ float red[4];
    int lane = threadIdx.x & 63, wave = threadIdx.x >> 6;
    if (lane == 0) red[wave] = sum;
    __syncthreads();
    if (threadIdx.x == 0)
        atomicAdd(out, (red[0] + red[1] + red[2] + red[3]) * inv_n);
}

extern "C" void kernel_launch(void* const* d_in, const int* in_sizes, int n_in,
                              void* d_out, int out_size, void* d_ws, size_t ws_size,
                              hipStream_t stream) {
    const float* pred  = (const float*)d_in[0];
    const int*   cidx  = (const int*)d_in[1];
    const int*   vidx  = (const int*)d_in[2];
    const float* coeff = (const float*)d_in[3];
    const float* rhs   = (const float*)d_in[4];
    const int*   sense = (const int*)d_in[5];

    const int n_vars    = in_sizes[0];
    const int nnz       = in_sizes[1];
    const int n_constrs = in_sizes[4];
    const int nb        = (n_constrs + W - 1) >> WSHIFT;

    // ---- workspace layout ----
    size_t off = 0;
    auto take = [&](size_t bytes) -> char* {
        char* p = (char*)d_ws + off;
        off = (off + bytes + 255) & ~(size_t)255;
        return p;
    };
    unsigned short* values = (unsigned short*)take((size_t)n_vars * 2);
    float*          ax_dev = (float*)take((size_t)n_constrs * 4);
    int*            cursor = (int*)take((size_t)(nb > 0 ? nb : 1) * 4);

    // region capacity per bucket: want mean + ~3%, floor at mean + 2048 (~5 sigma)
    size_t mean_per_bucket = (nb > 0) ? (size_t)nnz / (size_t)nb : 0;
    size_t cap_want  = mean_per_bucket + mean_per_bucket / 32 + 1024;
    size_t remaining = (ws_size > off) ? (ws_size - off) : 0;
    size_t cap_fit   = (nb > 0) ? remaining / ((size_t)nb * 6 + 16) : 0;  // 4B gp + 2B gc
    size_t cap       = (cap_want < cap_fit) ? cap_want : cap_fit;
    bool binned = (nb > 0) && (nb <= NB_MAX) && (cap >= mean_per_bucket + 2048);

    (void)hipMemsetAsync(ax_dev, 0, (size_t)n_constrs * sizeof(float), stream);
    (void)hipMemsetAsync(d_out, 0, sizeof(float), stream);

    {
        int threads = 256;
        int blocks = ((n_vars >> 2) + threads - 1) / threads;
        if (blocks < 1) blocks = 1;
        sigmoid_kernel<<<blocks, threads, 0, stream>>>(pred, values, n_vars);
    }

    if (binned) {
        float* gp = (float*)take((size_t)nb * cap * 4);
        unsigned short* gc = (unsigned short*)take((size_t)nb * cap * 2);
        (void)hipMemsetAsync(cursor, 0, (size_t)nb * sizeof(int), stream);

        bin_kernel<<<512, 256, 0, stream>>>(cidx, vidx, coeff, values,
                                            gp, gc, cursor, ax_dev,
                                            nnz, nb, (int)cap);
        accum_kernel<<<nb, 256, 0, stream>>>(gp, gc, cursor, ax_dev,
                                             rhs, sense, (float*)d_out,
                                             n_constrs, (int)cap,
                                             1.0f / (float)n_constrs);
    } else {
        int threads = 256;
        int blocks = (nnz + threads - 1) / threads;
        if (blocks > 8192) blocks = 8192;
        scatter_fallback_kernel<<<blocks, threads, 0, stream>>>(
            cidx, vidx, coeff, values, ax_dev, nnz);
        int rblocks = (n_constrs + threads - 1) / threads;
        if (rblocks > 4096) rblocks = 4096;
        viol_reduce_kernel<<<rblocks, threads, 0, stream>>>(
            ax_dev, rhs, sense, (float*)d_out, n_constrs,
            1.0f / (float)n_constrs);
    }
}